// Round 12
// baseline (81.071 us; speedup 1.0000x reference)
//
#include <hip/hip_runtime.h>

typedef _Float16 half4v __attribute__((ext_vector_type(4)));
typedef __fp16 fp16x2 __attribute__((ext_vector_type(2)));
typedef float float4v __attribute__((ext_vector_type(4)));

#define S_ 1024
#define H_ 8
#define B_ 8
#define BH 64           // B*H
#define NROW 8192       // B*S
#define E_ 64
#define VST 1032        // vT row stride (halves)

// Pack 4 floats -> half4v via v_cvt_pkrtz_f16_f32.
static __device__ inline half4v pack4(float a, float b, float c, float d) {
    union { fp16x2 f2[2]; half4v h4; } u;
    u.f2[0] = __builtin_amdgcn_cvt_pkrtz(a, b);
    u.f2[1] = __builtin_amdgcn_cvt_pkrtz(c, d);
    return u.h4;
}

// ---------------------------------------------------------------------------
// exp2 WITHOUT the transcendental unit (R12 experiment): the attn plateau
// (~23.5 us across 5 structures) fits a scarce-trans-pipe model (~13.7 us
// for 1.05M v_exp_f32 at ~per-CU rate), not the per-SIMD model (3.4 us).
// Full-rate FMA-pipe replacement: n=rint(s), f=s-n in [-1/2,1/2],
// 2^f deg-4 Taylor (rel err ~4e-5 << f16 pack err), 2^n by integer exponent.
// |s| <= 4.081 -> i in [-5,5], (127+i)<<23 always valid.
// ---------------------------------------------------------------------------
static __device__ inline float exp2p(float s) {
    float n = __builtin_rintf(s);           // v_rndne_f32
    float f = s - n;
    float p = 9.61812911e-3f;               // ln2^4/24
    p = __builtin_fmaf(p, f, 5.55041087e-2f);
    p = __builtin_fmaf(p, f, 2.40226507e-1f);
    p = __builtin_fmaf(p, f, 6.93147181e-1f);
    p = __builtin_fmaf(p, f, 1.0f);
    int i = (int)n;                          // v_cvt_i32_f32
    float sc = __int_as_float((127 + i) << 23);
    return p * sc;
}

static __device__ inline half4v pexp4(float4v s) {
    return pack4(exp2p(s[0]), exp2p(s[1]), exp2p(s[2]), exp2p(s[3]));
}

// ---------------------------------------------------------------------------
// Fused quantum-proj + MFMA flash attention per (b,h), O^T formulation.
// Structure IDENTICAL to R10 (best so far) except exp2 -> exp2p poly.
// Closed form: proj_w = prod_{i=0..w} cos(x_i+th_i) (w>=1); proj_0 = prod_{1..7}.
// kF: pre-swizzled K-frags (lanes 32..63 mirror, nullified by qf=0);
// vT: transposed V + ones row (l-trick); V-frag cols 9..15 mirror 1..7.
// J=4 independent key-quarter chains per wave, BFS-ordered, full unroll.
// mfma1: A=K-frag, B=Q-frag -> S^T == B-layout of P. P = exp2(S), no shift.
// mfma2: A=V'-frag, B=P -> O^T; ones row gives l at lane 32|q, reg 0.
// Grid (64,16)=1024 blocks = 4 blocks/CU (LDS 34.6 KB), 16 waves/CU.
// ---------------------------------------------------------------------------
__global__ __launch_bounds__(256, 4) void attn_kernel(
        const float* __restrict__ x, const float* __restrict__ theta,
        _Float16* __restrict__ attnH) {
    __shared__ _Float16 kF[64 * 128];       // 16384 B
    __shared__ _Float16 vT[9 * VST];        // 18576 B
    int bh = blockIdx.x;
    int b = bh >> 3, h = bh & 7;
    int tid = threadIdx.x;

    float th[8];
#pragma unroll
    for (int i = 0; i < 8; ++i) th[i] = theta[i];

    // ones row (l-trick): 256 threads x 4 halves = 1024
    {
        const half4v one = {(_Float16)1.f, (_Float16)1.f, (_Float16)1.f, (_Float16)1.f};
        *(half4v*)&vT[8 * VST + tid * 4] = one;
    }

    // ---- stage: closed-form quantum heads -> kF (swizzled) + vT (transposed)
    for (int s = tid; s < S_; s += 256) {
        const float4* xp = (const float4*)(x + (((size_t)(b << 10) + s) << 6) + (h << 3));
        float4 x0 = xp[0];
        float4 x1 = xp[1];
        float c0 = __cosf(x0.x + th[0]);
        float c1 = __cosf(x0.y + th[1]);
        float c2 = __cosf(x0.z + th[2]);
        float c3 = __cosf(x0.w + th[3]);
        float c4 = __cosf(x1.x + th[4]);
        float c5 = __cosf(x1.y + th[5]);
        float c6 = __cosf(x1.z + th[6]);
        float c7 = __cosf(x1.w + th[7]);
        float e1 = c0 * c1;
        float e2 = e1 * c2;
        float e3 = e2 * c3;
        float e4 = e3 * c4;
        float e5 = e4 * c5;
        float e6 = e5 * c6;
        float e7 = e6 * c7;
        float e0 = ((c1 * c2) * (c3 * c4)) * ((c5 * c6) * c7);
        half4v lo = pack4(e0, e1, e2, e3);
        half4v hi = pack4(e4, e5, e6, e7);
        int kt = s >> 4, c = s & 15;
        *(half4v*)&kF[kt * 128 + c * 4]      = lo;  // lane (q=0,c): d0..3
        *(half4v*)&kF[kt * 128 + 64 + c * 4] = hi;  // lane (q=1,c): d4..7
        vT[0 * VST + s] = lo[0]; vT[1 * VST + s] = lo[1];
        vT[2 * VST + s] = lo[2]; vT[3 * VST + s] = lo[3];
        vT[4 * VST + s] = hi[0]; vT[5 * VST + s] = hi[1];
        vT[6 * VST + s] = hi[2]; vT[7 * VST + s] = hi[3];
    }
    __syncthreads();

    int lane = tid & 63;
    int wv   = tid >> 6;
    int col  = lane & 15;
    int quad = lane >> 4;
    int q0   = blockIdx.y * 64 + wv * 16;   // 16 queries per wave

    bool lo2 = (quad < 2);

    // K-frag base: lanes 32..63 mirror 0..31 (A[k>=8] garbage nullified by qf)
    int kbase = (lane & 31) * 4;
    // V'-frag base: cols 9..15 mirror 1..7 (junk O^T rows never read)
    int vcol = (col < 9) ? col : (col - 8);
    int vbase = vcol * VST + quad * 4;

    // Q-frag (loop-invariant B of mfma1): quads>=2 ZERO -> kills K garbage
    half4v qf = {(_Float16)0.f, (_Float16)0.f, (_Float16)0.f, (_Float16)0.f};
    if (lo2) qf = *(const half4v*)&kF[kbase + (q0 >> 4) * 128];
    qf *= (_Float16)0.51012921f;            // log2(e)/sqrt(8)

    const float4v zc = {0.f, 0.f, 0.f, 0.f};
    float4v o0 = zc, o1 = zc, o2 = zc, o3 = zc;

#pragma unroll
    for (int kt = 0; kt < 16; ++kt) {
        // ---- BFS: 4 independent chains over key quarters ----
        half4v k0 = *(const half4v*)&kF[kbase + (kt +  0) * 128];
        half4v k1 = *(const half4v*)&kF[kbase + (kt + 16) * 128];
        half4v k2 = *(const half4v*)&kF[kbase + (kt + 32) * 128];
        half4v k3 = *(const half4v*)&kF[kbase + (kt + 48) * 128];
        half4v v0 = *(const half4v*)&vT[vbase + (kt +  0) * 16];
        half4v v1 = *(const half4v*)&vT[vbase + (kt + 16) * 16];
        half4v v2 = *(const half4v*)&vT[vbase + (kt + 32) * 16];
        half4v v3 = *(const half4v*)&vT[vbase + (kt + 48) * 16];
        float4v s0 = __builtin_amdgcn_mfma_f32_16x16x16f16(k0, qf, zc, 0, 0, 0);
        float4v s1 = __builtin_amdgcn_mfma_f32_16x16x16f16(k1, qf, zc, 0, 0, 0);
        float4v s2 = __builtin_amdgcn_mfma_f32_16x16x16f16(k2, qf, zc, 0, 0, 0);
        float4v s3 = __builtin_amdgcn_mfma_f32_16x16x16f16(k3, qf, zc, 0, 0, 0);
        half4v p0 = pexp4(s0);
        half4v p1 = pexp4(s1);
        half4v p2 = pexp4(s2);
        half4v p3 = pexp4(s3);
        o0 = __builtin_amdgcn_mfma_f32_16x16x16f16(v0, p0, o0, 0, 0, 0);
        o1 = __builtin_amdgcn_mfma_f32_16x16x16f16(v1, p1, o1, 0, 0, 0);
        o2 = __builtin_amdgcn_mfma_f32_16x16x16f16(v2, p2, o2, 0, 0, 0);
        o3 = __builtin_amdgcn_mfma_f32_16x16x16f16(v3, p3, o3, 0, 0, 0);
    }

    float4v oacc;
#pragma unroll
    for (int r = 0; r < 4; ++r) oacc[r] = (o0[r] + o1[r]) + (o2[r] + o3[r]);

    // l[q] = ones-row (row 8 of O^T): lane 32|q, reg 0.
    float l = __shfl(oacc[0], 32 | col, 64);
    if (lo2) {
        float inv = __builtin_amdgcn_rcpf(l);
        half4v ov = pack4(oacc[0] * inv, oacc[1] * inv, oacc[2] * inv, oacc[3] * inv);
        *(half4v*)(attnH + (((size_t)(b << 10) + q0 + col) << 6) + (h << 3) + quad * 4) = ov;
    }
}

// ---------------------------------------------------------------------------
// MFMA combine: out[r,e] = sum_k A[r,k] * W[e,k], A f16 [8192][64], W f32.
// Block = 64 rows, 4 waves. W-frags loop-invariant; 16 MFMAs per wave.
// ---------------------------------------------------------------------------
__global__ __launch_bounds__(256) void combine_kernel(
        const _Float16* __restrict__ AH, const float* __restrict__ W,
        float* __restrict__ out) {
    __shared__ _Float16 a2[64 * 68];
    __shared__ _Float16 wt[64 * 68];        // wt[k*68+e] = W[e][k]
    int r0 = blockIdx.x * 64;
    int tid = threadIdx.x;

    for (int idx = tid; idx < E_ * E_; idx += 256) {
        int e = idx >> 6, k = idx & 63;
        wt[k * 68 + e] = (_Float16)W[idx];
    }
#pragma unroll
    for (int j = 0; j < 4; ++j) {
        int off = tid * 16 + j * 4;         // 0..4095
        int row = off >> 6, k = off & 63;
        *(half4v*)&a2[row * 68 + k] = *(const half4v*)&AH[(size_t)r0 * E_ + off];
    }
    __syncthreads();

    int lane = tid & 63;
    int wv   = tid >> 6;
    int col  = lane & 15;
    int quad = lane >> 4;

    // W-frags: B[k=t*16+quad*4+j][n=e0*16+col]
    half4v wf[4][4];
#pragma unroll
    for (int t = 0; t < 4; ++t)
#pragma unroll
        for (int e = 0; e < 4; ++e) {
            int kb = (t * 16 + quad * 4) * 68 + e * 16 + col;
            half4v w_ = {wt[kb], wt[kb + 68], wt[kb + 136], wt[kb + 204]};
            wf[t][e] = w_;
        }

    float4v acc[4] = {{0,0,0,0},{0,0,0,0},{0,0,0,0},{0,0,0,0}};
#pragma unroll
    for (int t = 0; t < 4; ++t) {
        half4v af = *(const half4v*)&a2[(wv * 16 + col) * 68 + t * 16 + quad * 4];
#pragma unroll
        for (int e = 0; e < 4; ++e)
            acc[e] = __builtin_amdgcn_mfma_f32_16x16x16f16(af, wf[t][e], acc[e], 0, 0, 0);
    }

#pragma unroll
    for (int e = 0; e < 4; ++e)
#pragma unroll
        for (int r = 0; r < 4; ++r)
            out[(size_t)(r0 + wv * 16 + quad * 4 + r) * E_ + e * 16 + col] = acc[e][r];
}

// ---------------------------------------------------------------------------
extern "C" void kernel_launch(void* const* d_in, const int* in_sizes, int n_in,
                              void* d_out, int out_size, void* d_ws, size_t ws_size,
                              hipStream_t stream) {
    const float* x     = (const float*)d_in[0];   // [8,1024,64] fp32
    const float* theta = (const float*)d_in[1];   // [8]
    const float* W     = (const float*)d_in[2];   // [64,64]
    float* out = (float*)d_out;                   // [8,1024,64]

    _Float16* attnH = (_Float16*)d_ws;            // [8192][64] f16 : 1 MB

    attn_kernel<<<dim3(BH, S_ / 64), 256, 0, stream>>>(x, theta, attnH);
    combine_kernel<<<NROW / 64, 256, 0, stream>>>(attnH, W, out);
}

// Round 13
// 75.186 us; speedup vs baseline: 1.0783x; 1.0783x over previous
//
#include <hip/hip_runtime.h>

typedef _Float16 half4v __attribute__((ext_vector_type(4)));
typedef __fp16 fp16x2 __attribute__((ext_vector_type(2)));
typedef float float4v __attribute__((ext_vector_type(4)));

#define S_ 1024
#define H_ 8
#define B_ 8
#define BH 64           // B*H
#define NROW 8192       // B*S
#define E_ 64
#define VST2 520        // vT row stride (halves), 512 keys + pad
#define PSTR 12         // partial row stride (floats): 8 o + 1 l + 3 pad
#define KHOFF (64 * 1024 * PSTR)   // part[] offset for kh=1

// Pack 4 floats -> half4v via v_cvt_pkrtz_f16_f32.
static __device__ inline half4v pack4(float a, float b, float c, float d) {
    union { fp16x2 f2[2]; half4v h4; } u;
    u.f2[0] = __builtin_amdgcn_cvt_pkrtz(a, b);
    u.f2[1] = __builtin_amdgcn_cvt_pkrtz(c, d);
    return u.h4;
}

// ---------------------------------------------------------------------------
// R13: SPLIT-K flash attention. R12's slope experiment showed attn is
// latency/issue-bound (marginal VALU ~1:1 to time) while static pipe sums
// say ~5 us -- a latency-hiding shortfall at 16 waves/CU. Fix: halve the
// key range per block (512 keys), shrinking LDS to 17.4 KB -> 8 blocks/CU
// = 32 waves/CU (CU max, 2x R10). Each block writes UNNORMALIZED partial
// (O^T, l) in f32; combine merges the two halves.
//
// kF[kt<32][128]: pre-swizzled K-frags for this block's 512 keys
//   (lanes 32..63 mirror 0..31; garbage k>=8 nullified by qf=0 at quads>=2).
// qF[4][128]:  same layout for the block's own 64 q rows (separate array
//   since q-range may lie in the other key-half).
// vT[d<9][520]: transposed V + ones row (row 8 -> l in O^T row 8);
//   V-frag cols 9..15 mirror cols 1..7 (junk O^T rows never read).
// mfma1: A=K-frag, B=Q-frag -> S^T == B-layout of P. P = exp2(S), no shift
// (uniform scaling cancels in o/l after the cross-half merge too).
// mfma2: A=V'-frag, B=P -> O^T. J=2 chains, unroll-4 (VGPR <= 64 target).
// Grid (64,16,2) = 2048 blocks = 8/CU. launch_bounds(256,8).
// ---------------------------------------------------------------------------
__global__ __launch_bounds__(256, 8) void attn_kernel(
        const float* __restrict__ x, const float* __restrict__ theta,
        float* __restrict__ part) {
    __shared__ _Float16 kF[32 * 128];       // 8192 B
    __shared__ _Float16 qF[4 * 128];        // 1024 B
    __shared__ _Float16 vT[9 * VST2];       // 9360 B
    int bh = blockIdx.x;
    int qt = blockIdx.y;
    int kh = blockIdx.z;
    int b = bh >> 3, h = bh & 7;
    int tid = threadIdx.x;

    float th[8];
#pragma unroll
    for (int i = 0; i < 8; ++i) th[i] = theta[i];

    // ---- stage K/V rows (512 keys of this half) + ones row ----
#pragma unroll
    for (int i = 0; i < 2; ++i) {
        int sl = tid + i * 256;             // 0..511 local key
        int sg = (kh << 9) + sl;            // global s
        const float4* xp = (const float4*)(x + (((size_t)(b << 10) + sg) << 6) + (h << 3));
        float4 x0 = xp[0];
        float4 x1 = xp[1];
        float c0 = __cosf(x0.x + th[0]);
        float c1 = __cosf(x0.y + th[1]);
        float c2 = __cosf(x0.z + th[2]);
        float c3 = __cosf(x0.w + th[3]);
        float c4 = __cosf(x1.x + th[4]);
        float c5 = __cosf(x1.y + th[5]);
        float c6 = __cosf(x1.z + th[6]);
        float c7 = __cosf(x1.w + th[7]);
        float e1 = c0 * c1;
        float e2 = e1 * c2;
        float e3 = e2 * c3;
        float e4 = e3 * c4;
        float e5 = e4 * c5;
        float e6 = e5 * c6;
        float e7 = e6 * c7;
        float e0 = ((c1 * c2) * (c3 * c4)) * ((c5 * c6) * c7);
        half4v lo = pack4(e0, e1, e2, e3);
        half4v hi = pack4(e4, e5, e6, e7);
        int kt = sl >> 4, c = sl & 15;
        *(half4v*)&kF[kt * 128 + c * 4]      = lo;
        *(half4v*)&kF[kt * 128 + 64 + c * 4] = hi;
        vT[0 * VST2 + sl] = lo[0]; vT[1 * VST2 + sl] = lo[1];
        vT[2 * VST2 + sl] = lo[2]; vT[3 * VST2 + sl] = lo[3];
        vT[4 * VST2 + sl] = hi[0]; vT[5 * VST2 + sl] = hi[1];
        vT[6 * VST2 + sl] = hi[2]; vT[7 * VST2 + sl] = hi[3];
        vT[8 * VST2 + sl] = (_Float16)1.0f;
    }
    // ---- stage the block's own 64 q rows ----
    if (tid < 64) {
        int sg = (qt << 6) + tid;
        const float4* xp = (const float4*)(x + (((size_t)(b << 10) + sg) << 6) + (h << 3));
        float4 x0 = xp[0];
        float4 x1 = xp[1];
        float c0 = __cosf(x0.x + th[0]);
        float c1 = __cosf(x0.y + th[1]);
        float c2 = __cosf(x0.z + th[2]);
        float c3 = __cosf(x0.w + th[3]);
        float c4 = __cosf(x1.x + th[4]);
        float c5 = __cosf(x1.y + th[5]);
        float c6 = __cosf(x1.z + th[6]);
        float c7 = __cosf(x1.w + th[7]);
        float e1 = c0 * c1;
        float e2 = e1 * c2;
        float e3 = e2 * c3;
        float e4 = e3 * c4;
        float e5 = e4 * c5;
        float e6 = e5 * c6;
        float e7 = e6 * c7;
        float e0 = ((c1 * c2) * (c3 * c4)) * ((c5 * c6) * c7);
        int kt = tid >> 4, c = tid & 15;
        *(half4v*)&qF[kt * 128 + c * 4]      = pack4(e0, e1, e2, e3);
        *(half4v*)&qF[kt * 128 + 64 + c * 4] = pack4(e4, e5, e6, e7);
    }
    __syncthreads();

    int lane = tid & 63;
    int wv   = tid >> 6;
    int col  = lane & 15;
    int quad = lane >> 4;
    bool lo2 = (quad < 2);

    int kbase = (lane & 31) * 4;
    int vcol  = (col < 9) ? col : (col - 8);
    int vbase = vcol * VST2 + quad * 4;

    // Q-frag: quads>=2 ZERO (kills K-frag mirror garbage)
    half4v qf = {(_Float16)0.f, (_Float16)0.f, (_Float16)0.f, (_Float16)0.f};
    if (lo2) qf = *(const half4v*)&qF[kbase + wv * 128];
    qf *= (_Float16)0.51012921f;            // log2(e)/sqrt(8)

    const float4v zc = {0.f, 0.f, 0.f, 0.f};
    float4v o0 = zc, o1 = zc;

#pragma unroll 4
    for (int kt = 0; kt < 16; ++kt) {
        half4v k0 = *(const half4v*)&kF[kbase + kt * 128];
        half4v k1 = *(const half4v*)&kF[kbase + (kt + 16) * 128];
        half4v v0 = *(const half4v*)&vT[vbase + kt * 16];
        half4v v1 = *(const half4v*)&vT[vbase + (kt + 16) * 16];
        float4v s0 = __builtin_amdgcn_mfma_f32_16x16x16f16(k0, qf, zc, 0, 0, 0);
        float4v s1 = __builtin_amdgcn_mfma_f32_16x16x16f16(k1, qf, zc, 0, 0, 0);
        half4v p0 = pack4(__builtin_amdgcn_exp2f(s0[0]), __builtin_amdgcn_exp2f(s0[1]),
                          __builtin_amdgcn_exp2f(s0[2]), __builtin_amdgcn_exp2f(s0[3]));
        half4v p1 = pack4(__builtin_amdgcn_exp2f(s1[0]), __builtin_amdgcn_exp2f(s1[1]),
                          __builtin_amdgcn_exp2f(s1[2]), __builtin_amdgcn_exp2f(s1[3]));
        o0 = __builtin_amdgcn_mfma_f32_16x16x16f16(v0, p0, o0, 0, 0, 0);
        o1 = __builtin_amdgcn_mfma_f32_16x16x16f16(v1, p1, o1, 0, 0, 0);
    }

    float4v oacc;
#pragma unroll
    for (int r = 0; r < 4; ++r) oacc[r] = o0[r] + o1[r];

    // l[q] = ones-row (O^T row 8): lane 32|q, reg 0.
    float l = __shfl(oacc[0], 32 | col, 64);
    int q = (qt << 6) + (wv << 4) + col;
    float* pp = part + ((size_t)((kh << 6) + bh) * 1024 + q) * PSTR;
    if (lo2)
        *(float4*)(pp + quad * 4) = make_float4(oacc[0], oacc[1], oacc[2], oacc[3]);
    if (quad == 0) pp[8] = l;
}

// ---------------------------------------------------------------------------
// combine: merge the 2 key-half partials (sum o, sum l, normalize, f16) then
// MFMA GEMM out[r,e] = sum_k a[r,k] * W[e,k]. Block = 64 rows, 4 waves.
// ---------------------------------------------------------------------------
__global__ __launch_bounds__(256) void combine_kernel(
        const float* __restrict__ part, const float* __restrict__ W,
        float* __restrict__ out) {
    __shared__ _Float16 a2[64 * 68];
    __shared__ _Float16 wt[64 * 68];        // wt[k*68+e] = W[e][k]
    int r0 = blockIdx.x * 64;
    int tid = threadIdx.x;

    for (int idx = tid; idx < E_ * E_; idx += 256) {
        int e = idx >> 6, k = idx & 63;
        wt[k * 68 + e] = (_Float16)W[idx];
    }
    // merge prologue: 512 (row,head) cells, 2 per thread (same row)
#pragma unroll
    for (int j = 0; j < 2; ++j) {
        int cell = tid * 2 + j;
        int lr = cell >> 3, h = cell & 7;
        int r = r0 + lr;
        int b = r >> 10, s = r & 1023;
        size_t base = ((size_t)((b << 3) + h) * 1024 + s) * PSTR;
        const float* p0 = part + base;
        const float* p1 = part + KHOFF + base;
        float4 a0 = *(const float4*)p0;
        float4 b0 = *(const float4*)(p0 + 4);
        float4 a1 = *(const float4*)p1;
        float4 b1 = *(const float4*)(p1 + 4);
        float inv = 1.0f / (p0[8] + p1[8]);
        *(half4v*)&a2[lr * 68 + h * 8]     = pack4((a0.x + a1.x) * inv, (a0.y + a1.y) * inv,
                                                   (a0.z + a1.z) * inv, (a0.w + a1.w) * inv);
        *(half4v*)&a2[lr * 68 + h * 8 + 4] = pack4((b0.x + b1.x) * inv, (b0.y + b1.y) * inv,
                                                   (b0.z + b1.z) * inv, (b0.w + b1.w) * inv);
    }
    __syncthreads();

    int lane = tid & 63;
    int wv   = tid >> 6;
    int col  = lane & 15;
    int quad = lane >> 4;

    // W-frags: B[k=t*16+quad*4+j][n=e0*16+col]
    half4v wf[4][4];
#pragma unroll
    for (int t = 0; t < 4; ++t)
#pragma unroll
        for (int e = 0; e < 4; ++e) {
            int kb = (t * 16 + quad * 4) * 68 + e * 16 + col;
            half4v w_ = {wt[kb], wt[kb + 68], wt[kb + 136], wt[kb + 204]};
            wf[t][e] = w_;
        }

    float4v acc[4] = {{0,0,0,0},{0,0,0,0},{0,0,0,0},{0,0,0,0}};
#pragma unroll
    for (int t = 0; t < 4; ++t) {
        half4v af = *(const half4v*)&a2[(wv * 16 + col) * 68 + t * 16 + quad * 4];
#pragma unroll
        for (int e = 0; e < 4; ++e)
            acc[e] = __builtin_amdgcn_mfma_f32_16x16x16f16(af, wf[t][e], acc[e], 0, 0, 0);
    }

#pragma unroll
    for (int e = 0; e < 4; ++e)
#pragma unroll
        for (int r = 0; r < 4; ++r)
            out[(size_t)(r0 + wv * 16 + quad * 4 + r) * E_ + e * 16 + col] = acc[e][r];
}

// ---------------------------------------------------------------------------
extern "C" void kernel_launch(void* const* d_in, const int* in_sizes, int n_in,
                              void* d_out, int out_size, void* d_ws, size_t ws_size,
                              hipStream_t stream) {
    const float* x     = (const float*)d_in[0];   // [8,1024,64] fp32
    const float* theta = (const float*)d_in[1];   // [8]
    const float* W     = (const float*)d_in[2];   // [64,64]
    float* out = (float*)d_out;                   // [8,1024,64]

    float* part = (float*)d_ws;                   // 2*64*1024*12 f32 : 6.3 MB

    attn_kernel<<<dim3(BH, S_ / 64, 2), 256, 0, stream>>>(x, theta, part);
    combine_kernel<<<NROW / 64, 256, 0, stream>>>(part, W, out);
}

// Round 14
// 72.442 us; speedup vs baseline: 1.1191x; 1.0379x over previous
//
#include <hip/hip_runtime.h>

typedef _Float16 half4v __attribute__((ext_vector_type(4)));
typedef __fp16 fp16x2 __attribute__((ext_vector_type(2)));
typedef float float4v __attribute__((ext_vector_type(4)));

#define S_ 1024
#define H_ 8
#define B_ 8
#define BH 64           // B*H
#define NROW 8192       // B*S
#define E_ 64
#define VST 1032        // vT row stride (halves)

// Pack 4 floats -> half4v via v_cvt_pkrtz_f16_f32 (RTZ, for P in attn).
static __device__ inline half4v pack4(float a, float b, float c, float d) {
    union { fp16x2 f2[2]; half4v h4; } u;
    u.f2[0] = __builtin_amdgcn_cvt_pkrtz(a, b);
    u.f2[1] = __builtin_amdgcn_cvt_pkrtz(c, d);
    return u.h4;
}

// RNE pack for W (keeps combine rounding identical to prior rounds).
static __device__ inline half4v pack4rne(float a, float b, float c, float d) {
    half4v r = {(_Float16)a, (_Float16)b, (_Float16)c, (_Float16)d};
    return r;
}

// ---------------------------------------------------------------------------
// attn_kernel: BYTE-IDENTICAL to R10 (best total, 73.0 us). Fused quantum-
// proj + MFMA flash attention per (b,h), O^T formulation, J=4 key-quarter
// chains. See R10 comments. Grid (64,16) = 4 blocks/CU.
// ---------------------------------------------------------------------------
__global__ __launch_bounds__(256, 4) void attn_kernel(
        const float* __restrict__ x, const float* __restrict__ theta,
        _Float16* __restrict__ attnH) {
    __shared__ _Float16 kF[64 * 128];       // 16384 B
    __shared__ _Float16 vT[9 * VST];        // 18576 B
    int bh = blockIdx.x;
    int b = bh >> 3, h = bh & 7;
    int tid = threadIdx.x;

    float th[8];
#pragma unroll
    for (int i = 0; i < 8; ++i) th[i] = theta[i];

    {
        const half4v one = {(_Float16)1.f, (_Float16)1.f, (_Float16)1.f, (_Float16)1.f};
        *(half4v*)&vT[8 * VST + tid * 4] = one;
    }

    for (int s = tid; s < S_; s += 256) {
        const float4* xp = (const float4*)(x + (((size_t)(b << 10) + s) << 6) + (h << 3));
        float4 x0 = xp[0];
        float4 x1 = xp[1];
        float c0 = __cosf(x0.x + th[0]);
        float c1 = __cosf(x0.y + th[1]);
        float c2 = __cosf(x0.z + th[2]);
        float c3 = __cosf(x0.w + th[3]);
        float c4 = __cosf(x1.x + th[4]);
        float c5 = __cosf(x1.y + th[5]);
        float c6 = __cosf(x1.z + th[6]);
        float c7 = __cosf(x1.w + th[7]);
        float e1 = c0 * c1;
        float e2 = e1 * c2;
        float e3 = e2 * c3;
        float e4 = e3 * c4;
        float e5 = e4 * c5;
        float e6 = e5 * c6;
        float e7 = e6 * c7;
        float e0 = ((c1 * c2) * (c3 * c4)) * ((c5 * c6) * c7);
        half4v lo = pack4(e0, e1, e2, e3);
        half4v hi = pack4(e4, e5, e6, e7);
        int kt = s >> 4, c = s & 15;
        *(half4v*)&kF[kt * 128 + c * 4]      = lo;
        *(half4v*)&kF[kt * 128 + 64 + c * 4] = hi;
        vT[0 * VST + s] = lo[0]; vT[1 * VST + s] = lo[1];
        vT[2 * VST + s] = lo[2]; vT[3 * VST + s] = lo[3];
        vT[4 * VST + s] = hi[0]; vT[5 * VST + s] = hi[1];
        vT[6 * VST + s] = hi[2]; vT[7 * VST + s] = hi[3];
    }
    __syncthreads();

    int lane = tid & 63;
    int wv   = tid >> 6;
    int col  = lane & 15;
    int quad = lane >> 4;
    int q0   = blockIdx.y * 64 + wv * 16;

    bool lo2 = (quad < 2);

    int kbase = (lane & 31) * 4;
    int vcol = (col < 9) ? col : (col - 8);
    int vbase = vcol * VST + quad * 4;

    half4v qf = {(_Float16)0.f, (_Float16)0.f, (_Float16)0.f, (_Float16)0.f};
    if (lo2) qf = *(const half4v*)&kF[kbase + (q0 >> 4) * 128];
    qf *= (_Float16)0.51012921f;            // log2(e)/sqrt(8)

    const float4v zc = {0.f, 0.f, 0.f, 0.f};
    float4v o0 = zc, o1 = zc, o2 = zc, o3 = zc;

#pragma unroll
    for (int kt = 0; kt < 16; ++kt) {
        half4v k0 = *(const half4v*)&kF[kbase + (kt +  0) * 128];
        half4v k1 = *(const half4v*)&kF[kbase + (kt + 16) * 128];
        half4v k2 = *(const half4v*)&kF[kbase + (kt + 32) * 128];
        half4v k3 = *(const half4v*)&kF[kbase + (kt + 48) * 128];
        half4v v0 = *(const half4v*)&vT[vbase + (kt +  0) * 16];
        half4v v1 = *(const half4v*)&vT[vbase + (kt + 16) * 16];
        half4v v2 = *(const half4v*)&vT[vbase + (kt + 32) * 16];
        half4v v3 = *(const half4v*)&vT[vbase + (kt + 48) * 16];
        float4v s0 = __builtin_amdgcn_mfma_f32_16x16x16f16(k0, qf, zc, 0, 0, 0);
        float4v s1 = __builtin_amdgcn_mfma_f32_16x16x16f16(k1, qf, zc, 0, 0, 0);
        float4v s2 = __builtin_amdgcn_mfma_f32_16x16x16f16(k2, qf, zc, 0, 0, 0);
        float4v s3 = __builtin_amdgcn_mfma_f32_16x16x16f16(k3, qf, zc, 0, 0, 0);
        half4v p0 = pack4(__builtin_amdgcn_exp2f(s0[0]), __builtin_amdgcn_exp2f(s0[1]),
                          __builtin_amdgcn_exp2f(s0[2]), __builtin_amdgcn_exp2f(s0[3]));
        half4v p1 = pack4(__builtin_amdgcn_exp2f(s1[0]), __builtin_amdgcn_exp2f(s1[1]),
                          __builtin_amdgcn_exp2f(s1[2]), __builtin_amdgcn_exp2f(s1[3]));
        half4v p2 = pack4(__builtin_amdgcn_exp2f(s2[0]), __builtin_amdgcn_exp2f(s2[1]),
                          __builtin_amdgcn_exp2f(s2[2]), __builtin_amdgcn_exp2f(s2[3]));
        half4v p3 = pack4(__builtin_amdgcn_exp2f(s3[0]), __builtin_amdgcn_exp2f(s3[1]),
                          __builtin_amdgcn_exp2f(s3[2]), __builtin_amdgcn_exp2f(s3[3]));
        o0 = __builtin_amdgcn_mfma_f32_16x16x16f16(v0, p0, o0, 0, 0, 0);
        o1 = __builtin_amdgcn_mfma_f32_16x16x16f16(v1, p1, o1, 0, 0, 0);
        o2 = __builtin_amdgcn_mfma_f32_16x16x16f16(v2, p2, o2, 0, 0, 0);
        o3 = __builtin_amdgcn_mfma_f32_16x16x16f16(v3, p3, o3, 0, 0, 0);
    }

    float4v oacc;
#pragma unroll
    for (int r = 0; r < 4; ++r) oacc[r] = (o0[r] + o1[r]) + (o2[r] + o3[r]);

    float l = __shfl(oacc[0], 32 | col, 64);
    if (lo2) {
        float inv = __builtin_amdgcn_rcpf(l);
        half4v ov = pack4(oacc[0] * inv, oacc[1] * inv, oacc[2] * inv, oacc[3] * inv);
        *(half4v*)(attnH + (((size_t)(b << 10) + q0 + col) << 6) + (h << 3) + quad * 4) = ov;
    }
}

// ---------------------------------------------------------------------------
// R14 combine: ZERO LDS, ZERO barriers, direct-from-global fragments.
// out[r,e] = sum_k A[r,k]*W[e,k]. Both operands are contiguous in exactly
// the MFMA fragment layout:
//   A-frag (m=col row, k=t*16+quad*4+j):  8 B of AH[(r0+col)*64 + ...]
//   W-frag (B[k][n=e*16+col]):           16 B of W[(e*16+col)*64 + ...]
// Grid 512 x 64 threads: one wave per 16-row m-tile, 16 MFMAs, loads
// pipeline freely on vmcnt (W is L2-hot after the first blocks). Replaces
// the 128-block LDS/barrier/scalar-read combine (suspected ~9 us of
// exposed latency at 0.5 blocks/CU).
// ---------------------------------------------------------------------------
__global__ __launch_bounds__(64) void combine_kernel(
        const _Float16* __restrict__ AH, const float* __restrict__ W,
        float* __restrict__ out) {
    int r0 = blockIdx.x * 16;
    int lane = threadIdx.x;
    int col = lane & 15;
    int quad = lane >> 4;

    // A-frags: 4 x 8 B loads
    half4v af[4];
#pragma unroll
    for (int t = 0; t < 4; ++t)
        af[t] = *(const half4v*)&AH[(size_t)(r0 + col) * 64 + t * 16 + quad * 4];

    float4v acc[4] = {{0,0,0,0},{0,0,0,0},{0,0,0,0},{0,0,0,0}};
#pragma unroll
    for (int e = 0; e < 4; ++e) {
#pragma unroll
        for (int t = 0; t < 4; ++t) {
            float4 w4 = *(const float4*)&W[(size_t)(e * 16 + col) * 64 + t * 16 + quad * 4];
            half4v wf = pack4rne(w4.x, w4.y, w4.z, w4.w);
            acc[e] = __builtin_amdgcn_mfma_f32_16x16x16f16(af[t], wf, acc[e], 0, 0, 0);
        }
    }

#pragma unroll
    for (int e = 0; e < 4; ++e)
#pragma unroll
        for (int r = 0; r < 4; ++r)
            out[(size_t)(r0 + quad * 4 + r) * E_ + e * 16 + col] = acc[e][r];
}

// ---------------------------------------------------------------------------
extern "C" void kernel_launch(void* const* d_in, const int* in_sizes, int n_in,
                              void* d_out, int out_size, void* d_ws, size_t ws_size,
                              hipStream_t stream) {
    const float* x     = (const float*)d_in[0];   // [8,1024,64] fp32
    const float* theta = (const float*)d_in[1];   // [8]
    const float* W     = (const float*)d_in[2];   // [64,64]
    float* out = (float*)d_out;                   // [8,1024,64]

    _Float16* attnH = (_Float16*)d_ws;            // [8192][64] f16 : 1 MB

    attn_kernel<<<dim3(BH, S_ / 64), 256, 0, stream>>>(x, theta, attnH);
    combine_kernel<<<NROW / 16, 64, 0, stream>>>(attnH, W, out);
}

// Round 15
// 72.310 us; speedup vs baseline: 1.1212x; 1.0018x over previous
//
#include <hip/hip_runtime.h>

typedef _Float16 half4v __attribute__((ext_vector_type(4)));
typedef __fp16 fp16x2 __attribute__((ext_vector_type(2)));
typedef float float4v __attribute__((ext_vector_type(4)));

#define S_ 1024
#define H_ 8
#define B_ 8
#define BH 64           // B*H
#define NROW 8192       // B*S
#define E_ 64
#define VST 1032        // vT row stride (halves)
#define VHALVES (9 * VST)        // 9288 halves = 18576 B per bh (16B-divisible)
#define VCHUNK (VHALVES / 8)     // 1161 uint4 chunks

// Pack 4 floats -> half4v via v_cvt_pkrtz_f16_f32.
static __device__ inline half4v pack4(float a, float b, float c, float d) {
    union { fp16x2 f2[2]; half4v h4; } u;
    u.f2[0] = __builtin_amdgcn_cvt_pkrtz(a, b);
    u.f2[1] = __builtin_amdgcn_cvt_pkrtz(c, d);
    return u.h4;
}

// ---------------------------------------------------------------------------
// proj_kernel: closed-form quantum heads computed ONCE per (b,h) (prior
// rounds redid this 16x inside every attn block -- ~4-6 us of serialized
// staging per CU). Writes the exact LDS images attn needs:
//   kG[bh][8192]: pre-swizzled K/Q-fragments (kF image)
//   vG[bh][9288]: transposed V rows 0..7 + ones row 8 (vT image, stride 1032)
// proj_w = prod_{i=0..w} cos(x_i+th_i) (w>=1); proj_0 = prod_{1..7}.
// ---------------------------------------------------------------------------
__global__ __launch_bounds__(256) void proj_kernel(
        const float* __restrict__ x, const float* __restrict__ theta,
        _Float16* __restrict__ kG, _Float16* __restrict__ vG) {
    int bh = blockIdx.x >> 2;
    int s  = ((blockIdx.x & 3) << 8) + threadIdx.x;
    int b = bh >> 3, h = bh & 7;

    const float4* xp = (const float4*)(x + (((size_t)(b << 10) + s) << 6) + (h << 3));
    float4 x0 = xp[0];
    float4 x1 = xp[1];
    float c0 = __cosf(x0.x + theta[0]);
    float c1 = __cosf(x0.y + theta[1]);
    float c2 = __cosf(x0.z + theta[2]);
    float c3 = __cosf(x0.w + theta[3]);
    float c4 = __cosf(x1.x + theta[4]);
    float c5 = __cosf(x1.y + theta[5]);
    float c6 = __cosf(x1.z + theta[6]);
    float c7 = __cosf(x1.w + theta[7]);
    float e1 = c0 * c1;
    float e2 = e1 * c2;
    float e3 = e2 * c3;
    float e4 = e3 * c4;
    float e5 = e4 * c5;
    float e6 = e5 * c6;
    float e7 = e6 * c7;
    float e0 = ((c1 * c2) * (c3 * c4)) * ((c5 * c6) * c7);
    half4v lo = pack4(e0, e1, e2, e3);
    half4v hi = pack4(e4, e5, e6, e7);

    _Float16* kgb = kG + (size_t)bh * 8192;
    _Float16* vgb = vG + (size_t)bh * VHALVES;
    int kt = s >> 4, c = s & 15;
    *(half4v*)&kgb[kt * 128 + c * 4]      = lo;   // lane (q=0,c): d0..3
    *(half4v*)&kgb[kt * 128 + 64 + c * 4] = hi;   // lane (q=1,c): d4..7
    // transposed V rows (coalesced u16 across consecutive s)
    vgb[0 * VST + s] = lo[0]; vgb[1 * VST + s] = lo[1];
    vgb[2 * VST + s] = lo[2]; vgb[3 * VST + s] = lo[3];
    vgb[4 * VST + s] = hi[0]; vgb[5 * VST + s] = hi[1];
    vgb[6 * VST + s] = hi[2]; vgb[7 * VST + s] = hi[3];
    // ones row (l-trick): sub-block 0 covers s=0..1023 via tid*4
    if ((blockIdx.x & 3) == 0) {
        const half4v one = {(_Float16)1.f, (_Float16)1.f, (_Float16)1.f, (_Float16)1.f};
        *(half4v*)&vgb[8 * VST + threadIdx.x * 4] = one;
    }
}

// ---------------------------------------------------------------------------
// attn_kernel: K-loop byte-identical to R10/R14 (best). Staging is now a
// dumb 35 KB uint4 global->LDS copy of the precomputed images (L2-hot,
// 64 KB per bh reused by 16 blocks) -- no cos, no scalar transposed writes,
// no dependent x-load chain. O^T formulation, J=4 key-quarter chains.
// kF: lanes 32..63 mirror 0..31 (garbage k>=8 nullified by qf=0 quads>=2);
// vT: V-frag cols 9..15 mirror 1..7 (junk O^T rows never read).
// mfma1: A=K-frag, B=Q-frag -> S^T == B-layout of P. P = exp2(S), no shift.
// mfma2: A=V'-frag, B=P -> O^T; ones row gives l at lane 32|q, reg 0.
// Grid (64,16)=1024 blocks = 4 blocks/CU (LDS 34.96 KB), 16 waves/CU.
// ---------------------------------------------------------------------------
__global__ __launch_bounds__(256, 4) void attn_kernel(
        const _Float16* __restrict__ kG, const _Float16* __restrict__ vG,
        _Float16* __restrict__ attnH) {
    __shared__ _Float16 kF[64 * 128];       // 16384 B
    __shared__ _Float16 vT[VHALVES];        // 18576 B
    int bh = blockIdx.x;
    int b = bh >> 3, h = bh & 7;
    int tid = threadIdx.x;

    // ---- stage: plain vector copy of the precomputed images ----
    {
        const uint4* kg4 = (const uint4*)(kG + (size_t)bh * 8192);
        uint4* kf4 = (uint4*)kF;
#pragma unroll
        for (int i = 0; i < 4; ++i) kf4[tid + i * 256] = kg4[tid + i * 256];
        const uint4* vg4 = (const uint4*)(vG + (size_t)bh * VHALVES);
        uint4* vt4 = (uint4*)vT;
#pragma unroll
        for (int i = 0; i < 4; ++i) vt4[tid + i * 256] = vg4[tid + i * 256];
        if (tid < VCHUNK - 1024) vt4[tid + 1024] = vg4[tid + 1024];
    }
    __syncthreads();

    int lane = tid & 63;
    int wv   = tid >> 6;
    int col  = lane & 15;
    int quad = lane >> 4;
    int q0   = blockIdx.y * 64 + wv * 16;

    bool lo2 = (quad < 2);

    int kbase = (lane & 31) * 4;
    int vcol = (col < 9) ? col : (col - 8);
    int vbase = vcol * VST + quad * 4;

    half4v qf = {(_Float16)0.f, (_Float16)0.f, (_Float16)0.f, (_Float16)0.f};
    if (lo2) qf = *(const half4v*)&kF[kbase + (q0 >> 4) * 128];
    qf *= (_Float16)0.51012921f;            // log2(e)/sqrt(8)

    const float4v zc = {0.f, 0.f, 0.f, 0.f};
    float4v o0 = zc, o1 = zc, o2 = zc, o3 = zc;

#pragma unroll
    for (int kt = 0; kt < 16; ++kt) {
        half4v k0 = *(const half4v*)&kF[kbase + (kt +  0) * 128];
        half4v k1 = *(const half4v*)&kF[kbase + (kt + 16) * 128];
        half4v k2 = *(const half4v*)&kF[kbase + (kt + 32) * 128];
        half4v k3 = *(const half4v*)&kF[kbase + (kt + 48) * 128];
        half4v v0 = *(const half4v*)&vT[vbase + (kt +  0) * 16];
        half4v v1 = *(const half4v*)&vT[vbase + (kt + 16) * 16];
        half4v v2 = *(const half4v*)&vT[vbase + (kt + 32) * 16];
        half4v v3 = *(const half4v*)&vT[vbase + (kt + 48) * 16];
        float4v s0 = __builtin_amdgcn_mfma_f32_16x16x16f16(k0, qf, zc, 0, 0, 0);
        float4v s1 = __builtin_amdgcn_mfma_f32_16x16x16f16(k1, qf, zc, 0, 0, 0);
        float4v s2 = __builtin_amdgcn_mfma_f32_16x16x16f16(k2, qf, zc, 0, 0, 0);
        float4v s3 = __builtin_amdgcn_mfma_f32_16x16x16f16(k3, qf, zc, 0, 0, 0);
        half4v p0 = pack4(__builtin_amdgcn_exp2f(s0[0]), __builtin_amdgcn_exp2f(s0[1]),
                          __builtin_amdgcn_exp2f(s0[2]), __builtin_amdgcn_exp2f(s0[3]));
        half4v p1 = pack4(__builtin_amdgcn_exp2f(s1[0]), __builtin_amdgcn_exp2f(s1[1]),
                          __builtin_amdgcn_exp2f(s1[2]), __builtin_amdgcn_exp2f(s1[3]));
        half4v p2 = pack4(__builtin_amdgcn_exp2f(s2[0]), __builtin_amdgcn_exp2f(s2[1]),
                          __builtin_amdgcn_exp2f(s2[2]), __builtin_amdgcn_exp2f(s2[3]));
        half4v p3 = pack4(__builtin_amdgcn_exp2f(s3[0]), __builtin_amdgcn_exp2f(s3[1]),
                          __builtin_amdgcn_exp2f(s3[2]), __builtin_amdgcn_exp2f(s3[3]));
        o0 = __builtin_amdgcn_mfma_f32_16x16x16f16(v0, p0, o0, 0, 0, 0);
        o1 = __builtin_amdgcn_mfma_f32_16x16x16f16(v1, p1, o1, 0, 0, 0);
        o2 = __builtin_amdgcn_mfma_f32_16x16x16f16(v2, p2, o2, 0, 0, 0);
        o3 = __builtin_amdgcn_mfma_f32_16x16x16f16(v3, p3, o3, 0, 0, 0);
    }

    float4v oacc;
#pragma unroll
    for (int r = 0; r < 4; ++r) oacc[r] = (o0[r] + o1[r]) + (o2[r] + o3[r]);

    float l = __shfl(oacc[0], 32 | col, 64);
    if (lo2) {
        float inv = __builtin_amdgcn_rcpf(l);
        half4v ov = pack4(oacc[0] * inv, oacc[1] * inv, oacc[2] * inv, oacc[3] * inv);
        *(half4v*)(attnH + (((size_t)(b << 10) + q0 + col) << 6) + (h << 3) + quad * 4) = ov;
    }
}

// ---------------------------------------------------------------------------
// combine (R14): zero LDS / zero barriers, direct-from-global fragments.
// out[r,e] = sum_k A[r,k]*W[e,k]; A-frag and W-frag are contiguous in
// exactly the MFMA fragment layout. One wave per 16-row m-tile.
// ---------------------------------------------------------------------------
__global__ __launch_bounds__(64) void combine_kernel(
        const _Float16* __restrict__ AH, const float* __restrict__ W,
        float* __restrict__ out) {
    int r0 = blockIdx.x * 16;
    int lane = threadIdx.x;
    int col = lane & 15;
    int quad = lane >> 4;

    half4v af[4];
#pragma unroll
    for (int t = 0; t < 4; ++t)
        af[t] = *(const half4v*)&AH[(size_t)(r0 + col) * 64 + t * 16 + quad * 4];

    float4v acc[4] = {{0,0,0,0},{0,0,0,0},{0,0,0,0},{0,0,0,0}};
#pragma unroll
    for (int e = 0; e < 4; ++e) {
#pragma unroll
        for (int t = 0; t < 4; ++t) {
            float4 w4 = *(const float4*)&W[(size_t)(e * 16 + col) * 64 + t * 16 + quad * 4];
            half4v wf = {(_Float16)w4.x, (_Float16)w4.y, (_Float16)w4.z, (_Float16)w4.w};
            acc[e] = __builtin_amdgcn_mfma_f32_16x16x16f16(af[t], wf, acc[e], 0, 0, 0);
        }
    }

#pragma unroll
    for (int e = 0; e < 4; ++e)
#pragma unroll
        for (int r = 0; r < 4; ++r)
            out[(size_t)(r0 + quad * 4 + r) * E_ + e * 16 + col] = acc[e][r];
}

// ---------------------------------------------------------------------------
extern "C" void kernel_launch(void* const* d_in, const int* in_sizes, int n_in,
                              void* d_out, int out_size, void* d_ws, size_t ws_size,
                              hipStream_t stream) {
    const float* x     = (const float*)d_in[0];   // [8,1024,64] fp32
    const float* theta = (const float*)d_in[1];   // [8]
    const float* W     = (const float*)d_in[2];   // [64,64]
    float* out = (float*)d_out;                   // [8,1024,64]

    _Float16* kG    = (_Float16*)d_ws;                          // 1 MB
    _Float16* vG    = (_Float16*)((char*)d_ws + (2 << 20));     // 1.2 MB
    _Float16* attnH = (_Float16*)((char*)d_ws + (4 << 20));     // 1 MB

    proj_kernel<<<BH * 4, 256, 0, stream>>>(x, theta, kG, vG);
    attn_kernel<<<dim3(BH, S_ / 64), 256, 0, stream>>>(kG, vG, attnH);
    combine_kernel<<<NROW / 16, 64, 0, stream>>>(attnH, W, out);
}